// Round 12
// baseline (350.273 us; speedup 1.0000x reference)
//
#include <hip/hip_runtime.h>

#define NU 50000
#define NI 50000
#define NE 800000
#define NLBL 200000
#define DIN 128
#define HID 256
#define DOUT 128

#define NSLICE 128
#define SLICE_SZ 6250    // 800000 / 128
#define QN 12500         // node quarter-range per hist/fill block
#define NQ 4

typedef unsigned short ushort_t;
typedef unsigned char uchar_t;
typedef __attribute__((ext_vector_type(8))) short bf16x8;
typedef __attribute__((ext_vector_type(4))) float f32x4;

__device__ __forceinline__ float bf2f(unsigned int u_shifted) {
    union { unsigned int i; float f; } v;
    v.i = u_shifted;
    return v.f;
}
__device__ __forceinline__ float bf_lo(unsigned int u) { return bf2f(u << 16); }
__device__ __forceinline__ float bf_hi(unsigned int u) { return bf2f(u & 0xffff0000u); }
__device__ __forceinline__ ushort_t f2bf(float f) {
    union { float f; unsigned int i; } v;
    v.f = f;
    unsigned int r = (v.i + 0x7FFFu + ((v.i >> 16) & 1u)) >> 16;
    return (ushort_t)r;
}
__device__ __forceinline__ void load_lds16(const ushort_t* g, ushort_t* s) {
    __builtin_amdgcn_global_load_lds(
        (const __attribute__((address_space(1))) void*)g,
        (__attribute__((address_space(3))) void*)s, 16, 0, 0);
}

#define CVT_PER 782
#define CVT_B (2 * CVT_PER)
#define SA_B 512
#define HIST_B (2 * NSLICE * NQ)   // 1024: (graph, slice, node-quarter)
#define SW_B 1563                  // sweep blocks: 64 nodes x 4 part-waves each

// ================= phase1: hist (uchar counters, 12.5 KB LDS) ∥ stage-A ∥ zero =========
// G_t = Wm_t1 @ Lb_t          [256,128]
// S_t = La_t + Wr_t1 @ Lb_t   [256,128]
struct P1Args {
    const int *eui, *eiu;
    uchar_t* cnt_s;
    const float *wm_ui1, *wr_ui1, *wm_iu1, *wr_iu1, *lin_i, *lin_u;
    float *G_i, *S_i, *G_u, *S_u;
    int* scan_part;
};

__global__ __launch_bounds__(256) void phase1(P1Args a) {
    __shared__ unsigned int cnt[QN / 4];   // 12.5 KB, byte-packed counters
    int b = blockIdx.x, t = threadIdx.x;
    if (b < HIST_B) {
        int g = b >> 9, s = (b >> 2) & 127, q = b & 3;
        for (int i = t; i < QN / 4; i += 256) cnt[i] = 0;
        __syncthreads();
        const int* dst = (g ? a.eiu : a.eui) + NE;
        int hbase = q * QN;
        int e0 = s * SLICE_SZ;
        for (int i = e0 + t; i < e0 + SLICE_SZ; i += 256) {
            int d = dst[i] - hbase;
            if ((unsigned)d < (unsigned)QN)
                atomicAdd(&cnt[d >> 2], 1u << ((d & 3) * 8));
        }
        __syncthreads();
        unsigned int* outp = (unsigned int*)(a.cnt_s + ((size_t)(g * NSLICE + s)) * 50000 + hbase);
        for (int i = t; i < QN / 4; i += 256) outp[i] = cnt[i];
    } else if (b < HIST_B + SA_B) {
        int r2 = b - HIST_B;          // [0, 512)
        int which = r2 >> 7;          // 0:G_i 1:S_i 2:G_u 3:S_u
        int e = (r2 & 127) * 256 + t; // [0, 32768)
        int k = e >> 7, n = e & 127;
        const float* W = (which == 0) ? a.wm_ui1 : (which == 1) ? a.wr_ui1
                       : (which == 2) ? a.wm_iu1 : a.wr_iu1;
        const float* L = (which < 2) ? a.lin_i : a.lin_u;
        float* O = (which == 0) ? a.G_i : (which == 1) ? a.S_i
                 : (which == 2) ? a.G_u : a.S_u;
        float s = (which & 1) ? L[k * 128 + n] : 0.f;  // S adds La
#pragma unroll 4
        for (int j = 0; j < HID; ++j) s += W[k * HID + j] * L[(HID + j) * 128 + n];
        O[k * 128 + n] = s;
    } else {
        if (t < 64) a.scan_part[t] = 0;
    }
}

// ===== k2: 4-wave coalesced sweep (blocks 0..SW_B) ∥ prep2 V+bz ∥ cvt ==================
// sweep block = 64 nodes; wave w handles slices [32w,32w+32) for all 64 nodes
// (lane = node -> coalesced 64B wave reads); cross-part base via LDS psum[4][64].
// Serial depth 32 (vs 128), 4x TLP vs round-11.
// V1_t = Wm_own0@S_t + Wr_oth0@G_t ; V2_t = Wr_own0@S_t ; V3_t = Wm_oth0@G_t
// bz_t = b_own0@S_t + b_oth0@G_t + b_own1@Lb_t + b_lin_t
struct K2Args {
    uchar_t* cnt_s;
    int* totals;
    int* scan_part;
    const float *wm_ui0, *wr_ui0, *wm_iu0, *wr_iu0;
    const float *G_i, *S_i, *G_u, *S_u;
    const float *b_ui0, *b_iu0, *b_ui1, *b_iu1, *lin_i, *lin_u, *bl_i, *bl_u;
    ushort_t *VT1_i, *VT2_i, *VT3_i, *VT1_u, *VT2_u, *VT3_u;
    float *bz_i, *bz_u;
    const float* xu; ushort_t* xbu; const float* xi; ushort_t* xbi;
};

__global__ __launch_bounds__(256) void k2_scan_prep_cvt(K2Args a) {
    __shared__ int psum[4][64];
    int b = blockIdx.x, t = threadIdx.x;
    if (b < SW_B) {
        if (b == 0 && t == 0) a.totals[100000] = 2 * NE;  // sentinel
        int l = t & 63, w = t >> 6;
        int node_g = b * 64 + l;
        bool ok = node_g < 100000;
        int g = ok ? (node_g / 50000) : 0;
        int node = node_g - g * 50000;
        size_t base = (size_t)g * NSLICE * 50000 + node;
        int c[32];
        int sum = 0;
        if (ok) {
#pragma unroll 4
            for (int k = 0; k < 32; ++k) {
                c[k] = a.cnt_s[base + (size_t)(w * 32 + k) * 50000];
                sum += c[k];
            }
        }
        psum[w][l] = sum;
        __syncthreads();
        int run = 0;
        for (int p = 0; p < w; ++p) run += psum[p][l];
        if (ok) {
#pragma unroll 4
            for (int k = 0; k < 32; ++k) {
                a.cnt_s[base + (size_t)(w * 32 + k) * 50000] = (uchar_t)run;
                run += c[k];
            }
        } else {
            run = 0;
        }
        if (w == 3) {
            // run = inclusive total = node degree
            if (ok) a.totals[node_g] = run;
            int s = ok ? run : 0;
#pragma unroll
            for (int off = 32; off > 0; off >>= 1) s += __shfl_down(s, off, 64);
            if (l == 0) atomicAdd(&a.scan_part[b >> 5], s);  // 2048-node chunks = 32 blocks
        }
    } else if (b < SW_B + 386) {
        int task = b - SW_B;  // [0, 386)
        if (task < 384) {
            int v = task >> 6;
            int e = (task & 63) * 256 + t;   // [0, 16384)
            int k = e >> 7, n = e & 127;     // k in [0,128)
            const float *A1, *X1, *A2 = nullptr, *X2 = nullptr;
            ushort_t* O;
            switch (v) {
                case 0: A1 = a.wm_ui0; X1 = a.S_i; A2 = a.wr_iu0; X2 = a.G_i; O = a.VT1_i; break;
                case 1: A1 = a.wr_ui0; X1 = a.S_i; O = a.VT2_i; break;
                case 2: A1 = a.wm_iu0; X1 = a.G_i; O = a.VT3_i; break;
                case 3: A1 = a.wm_iu0; X1 = a.S_u; A2 = a.wr_ui0; X2 = a.G_u; O = a.VT1_u; break;
                case 4: A1 = a.wr_iu0; X1 = a.S_u; O = a.VT2_u; break;
                default: A1 = a.wm_ui0; X1 = a.G_u; O = a.VT3_u; break;
            }
            float s = 0.f;
#pragma unroll 4
            for (int j = 0; j < HID; ++j) s += A1[k * HID + j] * X1[j * 128 + n];
            if (A2) {
#pragma unroll 4
                for (int j = 0; j < HID; ++j) s += A2[k * HID + j] * X2[j * 128 + n];
            }
            O[n * 128 + k] = f2bf(s);
        } else if (t < 128) {
            int user = task - 384;  // 0: item, 1: user
            int n = t;
            const float* S = user ? a.S_u : a.S_i;
            const float* G = user ? a.G_u : a.G_i;
            const float* b_own0 = user ? a.b_iu0 : a.b_ui0;
            const float* b_oth0 = user ? a.b_ui0 : a.b_iu0;
            const float* b_own1 = user ? a.b_iu1 : a.b_ui1;
            const float* lin = user ? a.lin_u : a.lin_i;
            const float* bl = user ? a.bl_u : a.bl_i;
            float* o = user ? a.bz_u : a.bz_i;
            float s = bl[n];
            for (int j = 0; j < HID; ++j)
                s += b_own0[j] * S[j * 128 + n] + b_oth0[j] * G[j * 128 + n] +
                     b_own1[j] * lin[(HID + j) * 128 + n];
            o[n] = s;
        }
    } else {
        int cb = b - (SW_B + 386);   // [0, CVT_B)
        int which = (cb >= CVT_PER);
        if (which) cb -= CVT_PER;
        const float4* in = (const float4*)(which ? a.xi : a.xu);
        uint2* outp = (uint2*)(which ? a.xbi : a.xbu);
        const int n4 = NU * DIN / 4;
#pragma unroll
        for (int k = 0; k < 8; ++k) {
            int i = cb * 2048 + k * 256 + t;
            if (i < n4) {
                float4 v = in[i];
                uint2 o;
                o.x = (unsigned int)f2bf(v.x) | ((unsigned int)f2bf(v.y) << 16);
                o.y = (unsigned int)f2bf(v.z) | ((unsigned int)f2bf(v.w) << 16);
                outp[i] = o;
            }
        }
    }
}

// ================= scan3: exclusive scan of totals (reads raw chunk partials) ==========
__global__ __launch_bounds__(256) void scan3(int* __restrict__ d, const int* __restrict__ part,
                                             int n, int nb) {
    __shared__ int wsum[4];
    __shared__ int blockoff_sh;
    int b = blockIdx.x, t = threadIdx.x;
    int lane = t & 63, wv = t >> 6;
    if (t < 64) {
        int v = (t < nb) ? part[t] : 0;
        int incl = v;
#pragma unroll
        for (int off = 1; off < 64; off <<= 1) {
            int tv = __shfl_up(incl, off, 64);
            if (t >= off) incl += tv;
        }
        if (t == b) blockoff_sh = incl - v;
    }
    int i0 = b * 2048 + t * 8;
    int v[8];
    int tsum = 0;
#pragma unroll
    for (int k = 0; k < 8; ++k) {
        v[k] = (i0 + k < n) ? d[i0 + k] : 0;
        tsum += v[k];
    }
    int incl = tsum;
#pragma unroll
    for (int off = 1; off < 64; off <<= 1) {
        int tv = __shfl_up(incl, off, 64);
        if (lane >= off) incl += tv;
    }
    if (lane == 63) wsum[wv] = incl;
    __syncthreads();
    int woff = 0;
    for (int w = 0; w < wv; ++w) woff += wsum[w];
    int run = blockoff_sh + woff + (incl - tsum);
#pragma unroll
    for (int k = 0; k < 8; ++k) {
        if (i0 + k < n) d[i0 + k] = run;
        run += v[k];
    }
}

// ================= fill: quarter-range, uchar slice-offsets -> packed-ushort LDS =======
__global__ __launch_bounds__(256) void fill_lds(const int* __restrict__ eui,
                                                const int* __restrict__ eiu,
                                                const uchar_t* __restrict__ cnt_s,
                                                const int* __restrict__ rowstart,
                                                ushort_t* __restrict__ csr) {
    __shared__ unsigned int off[QN / 2];
    int b = blockIdx.x, t = threadIdx.x;
    int g = b >> 9, s = (b >> 2) & 127, q = b & 3;
    int hbase = q * QN;
    const unsigned int* st =
        (const unsigned int*)(cnt_s + ((size_t)(g * NSLICE + s)) * 50000 + hbase);
    for (int i = t; i < QN / 4; i += 256) {
        unsigned int v = st[i];
        off[2 * i]     = (v & 0xffu) | ((v >> 8) & 0xffu) << 16;
        off[2 * i + 1] = ((v >> 16) & 0xffu) | ((v >> 24) & 0xffu) << 16;
    }
    __syncthreads();
    const int* src = g ? eiu : eui;
    const int* dst = src + NE;
    const int* rs = rowstart + g * 50000;
    int e0 = s * SLICE_SZ;
    for (int i = e0 + t; i < e0 + SLICE_SZ; i += 256) {
        int dd = dst[i];
        int d = dd - hbase;
        if ((unsigned)d < (unsigned)QN) {
            unsigned old = atomicAdd(&off[d >> 1], 1u << ((d & 1) * 16));
            int rel = (int)((old >> ((d & 1) * 16)) & 0xffffu);
            csr[(size_t)rs[dd] + rel] = (ushort_t)src[i];
        }
    }
}

// ================= DIN=128 gather mean aggregation v3: feature-half phases =============
struct AggJob { const int* sp; const ushort_t* csr; const ushort_t* x; ushort_t* out; int n; };
struct AggJobs2 { AggJob j[2]; };

__global__ __launch_bounds__(256) void agg_din(AggJobs2 js) {
    AggJob jb = js.j[blockIdx.y];
    const int half = blockIdx.z;
    int wave = (int)((blockIdx.x * 256u + threadIdx.x) >> 6);
    int lane = threadIdx.x & 63;
    const int l = lane & 15;    // edge slot / feature slot within half
    const int h = lane >> 4;    // row within quad
    int w4 = wave * 4;
    if (w4 >= jb.n) return;
    int w = w4 + h;
    int s0 = jb.sp[w];
    int s1 = jb.sp[w + 1];
    int cnt = s1 - s0;
    float sc = (cnt > 0) ? 1.0f / (float)cnt : 0.0f;
    int cmax = cnt;
    {
        int c1 = __shfl_xor(cmax, 16, 64); cmax = (cmax > c1) ? cmax : c1;
        int c2 = __shfl_xor(cmax, 32, 64); cmax = (cmax > c2) ? cmax : c2;
    }
    const uint2* xp = (const uint2*)jb.x + half * 16;  // row = 32 uint2; half = 16 uint2
    float f0 = 0.f, f1 = 0.f, f2 = 0.f, f3 = 0.f;
#define ACC4(m, u)                                                     \
    f0 = fmaf(m, bf_lo(u.x), f0); f1 = fmaf(m, bf_hi(u.x), f1);        \
    f2 = fmaf(m, bf_lo(u.y), f2); f3 = fmaf(m, bf_hi(u.y), f3);
    for (int chunk = 0; chunk < cmax; chunk += 16) {
        int mh = cnt - chunk;
        int safe = (mh > 0) ? ((l < mh) ? l : mh - 1) : 0;
        int vidx = (int)jb.csr[s0 + chunk + safe];
        int mm = cmax - chunk;
        if (mm > 16) mm = 16;
        int j = 0;
        for (; j + 3 < mm; j += 4) {
            int i0 = __shfl(vidx, j, 16);
            int i1 = __shfl(vidx, j + 1, 16);
            int i2 = __shfl(vidx, j + 2, 16);
            int i3 = __shfl(vidx, j + 3, 16);
            float m0 = (j < mh) ? 1.f : 0.f;
            float m1 = (j + 1 < mh) ? 1.f : 0.f;
            float m2 = (j + 2 < mh) ? 1.f : 0.f;
            float m3 = (j + 3 < mh) ? 1.f : 0.f;
            uint2 u0 = xp[(size_t)((j < mh) ? i0 : 0) * 32 + l];
            uint2 u1 = xp[(size_t)((j + 1 < mh) ? i1 : 0) * 32 + l];
            uint2 u2 = xp[(size_t)((j + 2 < mh) ? i2 : 0) * 32 + l];
            uint2 u3 = xp[(size_t)((j + 3 < mh) ? i3 : 0) * 32 + l];
            ACC4(m0, u0);
            ACC4(m1, u1);
            ACC4(m2, u2);
            ACC4(m3, u3);
        }
        for (; j < mm; ++j) {
            int i0 = __shfl(vidx, j, 16);
            float m0 = (j < mh) ? 1.f : 0.f;
            uint2 u0 = xp[(size_t)((j < mh) ? i0 : 0) * 32 + l];
            ACC4(m0, u0);
        }
    }
#undef ACC4
    uint2 o;
    o.x = (unsigned int)f2bf(f0 * sc) | ((unsigned int)f2bf(f1 * sc) << 16);
    o.y = (unsigned int)f2bf(f2 * sc) | ((unsigned int)f2bf(f3 * sc) << 16);
    ((uint2*)jb.out)[(size_t)w * 32 + half * 16 + l] = o;
}

// ================= MFMA GEMM: C = sum_p A[p]@W[p] + bias, NP parts, 2 jobs =================
struct GemmJob {
    const ushort_t* A[3];
    const ushort_t* WT[3];
    int K[3];
    const float* bias;
    void* C;
};
struct GemmJobs2 { GemmJob j[2]; };

template <int NP, typename OutT>
__global__ __launch_bounds__(256) void gemmN(GemmJobs2 js, int M, int N) {
    GemmJob jb = js.j[blockIdx.z];
    __shared__ ushort_t sA[128 * 32];
    __shared__ ushort_t sB[128 * 32];
    const int tid = threadIdx.x;
    const int lane = tid & 63;
    const int wv = tid >> 6;
    const int wm = wv & 1, wn = wv >> 1;
    const int bm = blockIdx.y * 128, bn = blockIdx.x * 128;

    f32x4 acc[4][4] = {};

    const int srow = tid >> 2;
    const int scol = (tid & 3) * 8;

#pragma unroll
    for (int part = 0; part < NP; ++part) {
        const ushort_t* A = jb.A[part];
        const ushort_t* WT = jb.WT[part];
        const int K = jb.K[part];
        int ar0 = bm + srow;       if (ar0 > M - 1) ar0 = M - 1;
        int ar1 = bm + 64 + srow;  if (ar1 > M - 1) ar1 = M - 1;
        const size_t aoff0 = (size_t)ar0 * K + scol;
        const size_t aoff1 = (size_t)ar1 * K + scol;
        const size_t boff0 = (size_t)(bn + srow) * K + scol;
        const size_t boff1 = (size_t)(bn + 64 + srow) * K + scol;
        for (int k0 = 0; k0 < K; k0 += 32) {
            __syncthreads();
            load_lds16(A + aoff0 + k0, sA + tid * 8);
            load_lds16(A + aoff1 + k0, sA + 2048 + tid * 8);
            load_lds16(WT + boff0 + k0, sB + tid * 8);
            load_lds16(WT + boff1 + k0, sB + 2048 + tid * 8);
            __syncthreads();
            const ushort_t* pA = sA + ((wm * 64 + (lane & 15)) * 32 + (lane >> 4) * 8);
            const ushort_t* pB = sB + ((wn * 64 + (lane & 15)) * 32 + (lane >> 4) * 8);
            bf16x8 af[4], bfr[4];
#pragma unroll
            for (int mt = 0; mt < 4; ++mt) af[mt] = *(const bf16x8*)(pA + mt * 512);
#pragma unroll
            for (int nt = 0; nt < 4; ++nt) bfr[nt] = *(const bf16x8*)(pB + nt * 512);
#pragma unroll
            for (int mt = 0; mt < 4; ++mt)
#pragma unroll
                for (int nt = 0; nt < 4; ++nt)
                    acc[mt][nt] = __builtin_amdgcn_mfma_f32_16x16x32_bf16(
                        af[mt], bfr[nt], acc[mt][nt], 0, 0, 0);
        }
    }

#pragma unroll
    for (int mt = 0; mt < 4; ++mt) {
#pragma unroll
        for (int r = 0; r < 4; ++r) {
            int row = bm + wm * 64 + mt * 16 + (lane >> 4) * 4 + r;
            if (row >= M) continue;
#pragma unroll
            for (int nt = 0; nt < 4; ++nt) {
                int col = bn + wn * 64 + nt * 16 + (lane & 15);
                float v = acc[mt][nt][r] + jb.bias[col];
                if constexpr (sizeof(OutT) == 2)
                    ((ushort_t*)jb.C)[(size_t)row * N + col] = f2bf(v);
                else
                    ((float*)jb.C)[(size_t)row * N + col] = v;
            }
        }
    }
}

// ================= decode: bf16 z, 4 edges per wave (16-lane quarters, uint4) =================
__global__ void decode_kernel(const int* __restrict__ lbl, const ushort_t* __restrict__ zu,
                              const ushort_t* __restrict__ zi, float* __restrict__ out, int n) {
    int gid = blockIdx.x * blockDim.x + threadIdx.x;
    int wave = gid >> 6;
    int lane = threadIdx.x & 63;
    int q = lane >> 4;
    int l = lane & 15;
    int e = wave * 4 + q;
    if (e >= n) return;
    int u = lbl[e];
    int it = lbl[n + e];
    uint4 a = ((const uint4*)zu)[(size_t)u * 16 + l];
    uint4 b = ((const uint4*)zi)[(size_t)it * 16 + l];
    float s = bf_lo(a.x) * bf_lo(b.x) + bf_hi(a.x) * bf_hi(b.x) +
              bf_lo(a.y) * bf_lo(b.y) + bf_hi(a.y) * bf_hi(b.y) +
              bf_lo(a.z) * bf_lo(b.z) + bf_hi(a.z) * bf_hi(b.z) +
              bf_lo(a.w) * bf_lo(b.w) + bf_hi(a.w) * bf_hi(b.w);
#pragma unroll
    for (int off = 8; off > 0; off >>= 1) s += __shfl_down(s, off, 16);
    if (l == 0) out[e] = s;
}

extern "C" void kernel_launch(void* const* d_in, const int* in_sizes, int n_in,
                              void* d_out, int out_size, void* d_ws, size_t ws_size,
                              hipStream_t stream) {
    const float* x_user = (const float*)d_in[0];
    const float* x_item = (const float*)d_in[1];
    const int* edge_ui = (const int*)d_in[2];   // row0=src(user), row1=dst(item)
    const int* edge_iu = (const int*)d_in[3];   // row0=src(item), row1=dst(user)
    const int* edge_lbl = (const int*)d_in[4];
    const float* w_msg_ui0 = (const float*)d_in[5];
    const float* b_ui0 = (const float*)d_in[6];
    const float* w_root_ui0 = (const float*)d_in[7];
    const float* w_msg_iu0 = (const float*)d_in[8];
    const float* b_iu0 = (const float*)d_in[9];
    const float* w_root_iu0 = (const float*)d_in[10];
    const float* w_msg_ui1 = (const float*)d_in[11];
    const float* b_ui1 = (const float*)d_in[12];
    const float* w_root_ui1 = (const float*)d_in[13];
    const float* w_msg_iu1 = (const float*)d_in[14];
    const float* b_iu1 = (const float*)d_in[15];
    const float* w_root_iu1 = (const float*)d_in[16];
    const float* w_lin_u = (const float*)d_in[17];  // [512,128]
    const float* b_lin_u = (const float*)d_in[18];
    const float* w_lin_i = (const float*)d_in[19];
    const float* b_lin_i = (const float*)d_in[20];
    float* out = (float*)d_out;

    // ---- workspace layout ----
    char* p = (char*)d_ws;
    ushort_t* A_i  = (ushort_t*)p;   p += (size_t)NI * DIN * 2;  // mean_ui(x_user)
    ushort_t* A_u  = (ushort_t*)p;   p += (size_t)NU * DIN * 2;  // mean_iu(x_item)
    ushort_t* B_i  = (ushort_t*)p;   p += (size_t)NI * DIN * 2;  // mean_ui(A_u)
    ushort_t* B_u  = (ushort_t*)p;   p += (size_t)NU * DIN * 2;  // mean_iu(A_i)
    ushort_t* xb_u  = (ushort_t*)p;  p += (size_t)NU * DIN * 2;
    ushort_t* xb_i  = (ushort_t*)p;  p += (size_t)NI * DIN * 2;
    ushort_t* z_user = (ushort_t*)p; p += (size_t)NU * DOUT * 2;
    ushort_t* z_item = (ushort_t*)p; p += (size_t)NI * DOUT * 2;
    int* totals     = (int*)p;       p += (size_t)(100000 + 64) * 4;  // rowstarts + sentinel
    ushort_t* csr   = (ushort_t*)p;  p += (size_t)2 * NE * 2;  // [0,NE): ui; [NE,2NE): iu
    uchar_t* cnt_s  = (uchar_t*)p;   p += (size_t)2 * NSLICE * 50000;  // per-slice uchar counts
    int* scan_part  = (int*)p;       p += 64 * 4;
    float* G_i = (float*)p; p += (size_t)HID * 128 * 4;
    float* S_i = (float*)p; p += (size_t)HID * 128 * 4;
    float* G_u = (float*)p; p += (size_t)HID * 128 * 4;
    float* S_u = (float*)p; p += (size_t)HID * 128 * 4;
    ushort_t* VT1_i = (ushort_t*)p; p += (size_t)128 * 128 * 2;
    ushort_t* VT2_i = (ushort_t*)p; p += (size_t)128 * 128 * 2;
    ushort_t* VT3_i = (ushort_t*)p; p += (size_t)128 * 128 * 2;
    ushort_t* VT1_u = (ushort_t*)p; p += (size_t)128 * 128 * 2;
    ushort_t* VT2_u = (ushort_t*)p; p += (size_t)128 * 128 * 2;
    ushort_t* VT3_u = (ushort_t*)p; p += (size_t)128 * 128 * 2;
    float* bz_i = (float*)p; p += 128 * 4;
    float* bz_u = (float*)p; p += 128 * 4;

    const int NCNT = 100000;
    const int NB = (NCNT + 2047) / 2048;  // 49

    // ---- 1: hist (uchar, quarter-range) ∥ stage-A products ∥ scan_part zero ----
    P1Args p1;
    p1.eui = edge_ui; p1.eiu = edge_iu; p1.cnt_s = cnt_s;
    p1.wm_ui1 = w_msg_ui1; p1.wr_ui1 = w_root_ui1;
    p1.wm_iu1 = w_msg_iu1; p1.wr_iu1 = w_root_iu1;
    p1.lin_i = w_lin_i; p1.lin_u = w_lin_u;
    p1.G_i = G_i; p1.S_i = S_i; p1.G_u = G_u; p1.S_u = S_u;
    p1.scan_part = scan_part;
    phase1<<<HIST_B + SA_B + 1, 256, 0, stream>>>(p1);

    // ---- 2: 4-wave coalesced sweep (+scan1 fold) ∥ prep2 V products + bz ∥ cvt ----
    K2Args k2;
    k2.cnt_s = cnt_s; k2.totals = totals; k2.scan_part = scan_part;
    k2.wm_ui0 = w_msg_ui0; k2.wr_ui0 = w_root_ui0;
    k2.wm_iu0 = w_msg_iu0; k2.wr_iu0 = w_root_iu0;
    k2.G_i = G_i; k2.S_i = S_i; k2.G_u = G_u; k2.S_u = S_u;
    k2.b_ui0 = b_ui0; k2.b_iu0 = b_iu0; k2.b_ui1 = b_ui1; k2.b_iu1 = b_iu1;
    k2.lin_i = w_lin_i; k2.lin_u = w_lin_u; k2.bl_i = b_lin_i; k2.bl_u = b_lin_u;
    k2.VT1_i = VT1_i; k2.VT2_i = VT2_i; k2.VT3_i = VT3_i;
    k2.VT1_u = VT1_u; k2.VT2_u = VT2_u; k2.VT3_u = VT3_u;
    k2.bz_i = bz_i; k2.bz_u = bz_u;
    k2.xu = x_user; k2.xbu = xb_u; k2.xi = x_item; k2.xbi = xb_i;
    k2_scan_prep_cvt<<<SW_B + 386 + CVT_B, 256, 0, stream>>>(k2);

    // ---- 3: global scan (scan3 reads raw chunk partials, scans internally) ----
    scan3<<<NB, 256, 0, stream>>>(totals, scan_part, NCNT, NB);

    // ---- 4: fill csr (quarter-range, 1024 blocks) ----
    fill_lds<<<HIST_B, 256, 0, stream>>>(edge_ui, edge_iu, cnt_s, totals, csr);

    // ---- 5: level-A aggregation (feature-half phases via blockIdx.z) ----
    {
        AggJobs2 aj = {{{totals, csr, xb_u, A_i, NI},
                        {totals + 50000, csr, xb_i, A_u, NU}}};
        agg_din<<<dim3(3125, 2, 2), 256, 0, stream>>>(aj);
    }
    // ---- 6: level-B aggregation: B_i = mean_ui(A_u), B_u = mean_iu(A_i) ----
    {
        AggJobs2 aj = {{{totals, csr, A_u, B_i, NI},
                        {totals + 50000, csr, A_i, B_u, NU}}};
        agg_din<<<dim3(3125, 2, 2), 256, 0, stream>>>(aj);
    }

    // ---- 7: single fused-weight GEMM: z = A@V1 + xb@V2 + B@V3 + bz ----
    {
        GemmJobs2 gj = {{{{A_i, xb_i, B_i}, {VT1_i, VT2_i, VT3_i}, {DIN, DIN, DIN}, bz_i, z_item},
                         {{A_u, xb_u, B_u}, {VT1_u, VT2_u, VT3_u}, {DIN, DIN, DIN}, bz_u, z_user}}};
        gemmN<3, ushort_t><<<dim3(DOUT / 128, (NU + 127) / 128, 2), 256, 0, stream>>>(gj, NU, DOUT);
    }

    // ---- 8: decode (4 edges per wave) ----
    decode_kernel<<<(((NLBL + 3) / 4) * 64 + 255) / 256, 256, 0, stream>>>(
        edge_lbl, z_user, z_item, out, NLBL);
}

// Round 13
// 345.515 us; speedup vs baseline: 1.0138x; 1.0138x over previous
//
#include <hip/hip_runtime.h>

#define NU 50000
#define NI 50000
#define NE 800000
#define NLBL 200000
#define DIN 128
#define HID 256
#define DOUT 128

#define NSLICE 128
#define SLICE_SZ 6250    // 800000 / 128
#define QN 12500         // node quarter-range per hist/fill block
#define NQ 4

typedef unsigned short ushort_t;
typedef unsigned char uchar_t;
typedef __attribute__((ext_vector_type(8))) short bf16x8;
typedef __attribute__((ext_vector_type(4))) float f32x4;

__device__ __forceinline__ float bf2f(unsigned int u_shifted) {
    union { unsigned int i; float f; } v;
    v.i = u_shifted;
    return v.f;
}
__device__ __forceinline__ float bf_lo(unsigned int u) { return bf2f(u << 16); }
__device__ __forceinline__ float bf_hi(unsigned int u) { return bf2f(u & 0xffff0000u); }
__device__ __forceinline__ ushort_t f2bf(float f) {
    union { float f; unsigned int i; } v;
    v.f = f;
    unsigned int r = (v.i + 0x7FFFu + ((v.i >> 16) & 1u)) >> 16;
    return (ushort_t)r;
}
__device__ __forceinline__ void load_lds16(const ushort_t* g, ushort_t* s) {
    __builtin_amdgcn_global_load_lds(
        (const __attribute__((address_space(1))) void*)g,
        (__attribute__((address_space(3))) void*)s, 16, 0, 0);
}

#define CVT_PER 782
#define CVT_B (2 * CVT_PER)
#define SA_B 512
#define HIST_B (2 * NSLICE * NQ)   // 1024: (graph, slice, node-quarter)
#define SW_B 392                   // sweep blocks: 1 thread per node (coalesced)

// ================= phase1: hist (uchar counters, 12.5 KB LDS) ∥ stage-A ∥ zero =========
// G_t = Wm_t1 @ Lb_t          [256,128]
// S_t = La_t + Wr_t1 @ Lb_t   [256,128]
struct P1Args {
    const int *eui, *eiu;
    uchar_t* cnt_s;
    const float *wm_ui1, *wr_ui1, *wm_iu1, *wr_iu1, *lin_i, *lin_u;
    float *G_i, *S_i, *G_u, *S_u;
    int* scan_part;
};

__global__ __launch_bounds__(256) void phase1(P1Args a) {
    __shared__ unsigned int cnt[QN / 4];   // 12.5 KB, byte-packed counters
    int b = blockIdx.x, t = threadIdx.x;
    if (b < HIST_B) {
        int g = b >> 9, s = (b >> 2) & 127, q = b & 3;
        for (int i = t; i < QN / 4; i += 256) cnt[i] = 0;
        __syncthreads();
        const int* dst = (g ? a.eiu : a.eui) + NE;
        int hbase = q * QN;
        int e0 = s * SLICE_SZ;
        for (int i = e0 + t; i < e0 + SLICE_SZ; i += 256) {
            int d = dst[i] - hbase;
            if ((unsigned)d < (unsigned)QN)
                atomicAdd(&cnt[d >> 2], 1u << ((d & 3) * 8));
        }
        __syncthreads();
        unsigned int* outp = (unsigned int*)(a.cnt_s + ((size_t)(g * NSLICE + s)) * 50000 + hbase);
        for (int i = t; i < QN / 4; i += 256) outp[i] = cnt[i];
    } else if (b < HIST_B + SA_B) {
        int r2 = b - HIST_B;          // [0, 512)
        int which = r2 >> 7;          // 0:G_i 1:S_i 2:G_u 3:S_u
        int e = (r2 & 127) * 256 + t; // [0, 32768)
        int k = e >> 7, n = e & 127;
        const float* W = (which == 0) ? a.wm_ui1 : (which == 1) ? a.wr_ui1
                       : (which == 2) ? a.wm_iu1 : a.wr_iu1;
        const float* L = (which < 2) ? a.lin_i : a.lin_u;
        float* O = (which == 0) ? a.G_i : (which == 1) ? a.S_i
                 : (which == 2) ? a.G_u : a.S_u;
        float s = (which & 1) ? L[k * 128 + n] : 0.f;  // S adds La
#pragma unroll 4
        for (int j = 0; j < HID; ++j) s += W[k * HID + j] * L[(HID + j) * 128 + n];
        O[k * 128 + n] = s;
    } else {
        if (t < 64) a.scan_part[t] = 0;
    }
}

// ===== k2: coalesced uchar sscan (blocks 0-391) ∥ prep2 V+bz ∥ cvt =====================
// sweep: 1 thread per node (consecutive lanes = consecutive nodes = coalesced 64B/wave);
// uchar counters halve line count vs ushort.
// V1_t = Wm_own0@S_t + Wr_oth0@G_t ; V2_t = Wr_own0@S_t ; V3_t = Wm_oth0@G_t
// bz_t = b_own0@S_t + b_oth0@G_t + b_own1@Lb_t + b_lin_t
struct K2Args {
    uchar_t* cnt_s;
    int* totals;
    int* scan_part;
    const float *wm_ui0, *wr_ui0, *wm_iu0, *wr_iu0;
    const float *G_i, *S_i, *G_u, *S_u;
    const float *b_ui0, *b_iu0, *b_ui1, *b_iu1, *lin_i, *lin_u, *bl_i, *bl_u;
    ushort_t *VT1_i, *VT2_i, *VT3_i, *VT1_u, *VT2_u, *VT3_u;
    float *bz_i, *bz_u;
    const float* xu; ushort_t* xbu; const float* xi; ushort_t* xbi;
};

__global__ __launch_bounds__(256) void k2_scan_prep_cvt(K2Args a) {
    __shared__ int wsum[4];
    int b = blockIdx.x, t = threadIdx.x;
    if (b < SW_B) {
        if (b == 0 && t == 0) a.totals[100000] = 2 * NE;  // sentinel
        int idx = b * 256 + t;
        int run = 0;
        if (idx < 100000) {
            int g = idx / 50000, node = idx - g * 50000;
            size_t base = (size_t)g * NSLICE * 50000 + node;
#pragma unroll 4
            for (int s = 0; s < NSLICE; ++s) {
                size_t o = base + (size_t)s * 50000;
                int c = a.cnt_s[o];
                a.cnt_s[o] = (uchar_t)run;
                run += c;
            }
            a.totals[idx] = run;
        }
        // fold scan1: block-reduce -> one atomicAdd into chunk partial (chunk = b/8)
        int s = run;
#pragma unroll
        for (int off = 32; off > 0; off >>= 1) s += __shfl_down(s, off, 64);
        if ((t & 63) == 0) wsum[t >> 6] = s;
        __syncthreads();
        if (t == 0) atomicAdd(&a.scan_part[b >> 3], wsum[0] + wsum[1] + wsum[2] + wsum[3]);
    } else if (b < SW_B + 386) {
        int task = b - SW_B;  // [0, 386)
        if (task < 384) {
            int v = task >> 6;
            int e = (task & 63) * 256 + t;   // [0, 16384)
            int k = e >> 7, n = e & 127;     // k in [0,128)
            const float *A1, *X1, *A2 = nullptr, *X2 = nullptr;
            ushort_t* O;
            switch (v) {
                case 0: A1 = a.wm_ui0; X1 = a.S_i; A2 = a.wr_iu0; X2 = a.G_i; O = a.VT1_i; break;
                case 1: A1 = a.wr_ui0; X1 = a.S_i; O = a.VT2_i; break;
                case 2: A1 = a.wm_iu0; X1 = a.G_i; O = a.VT3_i; break;
                case 3: A1 = a.wm_iu0; X1 = a.S_u; A2 = a.wr_ui0; X2 = a.G_u; O = a.VT1_u; break;
                case 4: A1 = a.wr_iu0; X1 = a.S_u; O = a.VT2_u; break;
                default: A1 = a.wm_ui0; X1 = a.G_u; O = a.VT3_u; break;
            }
            float s = 0.f;
#pragma unroll 4
            for (int j = 0; j < HID; ++j) s += A1[k * HID + j] * X1[j * 128 + n];
            if (A2) {
#pragma unroll 4
                for (int j = 0; j < HID; ++j) s += A2[k * HID + j] * X2[j * 128 + n];
            }
            O[n * 128 + k] = f2bf(s);
        } else if (t < 128) {
            int user = task - 384;  // 0: item, 1: user
            int n = t;
            const float* S = user ? a.S_u : a.S_i;
            const float* G = user ? a.G_u : a.G_i;
            const float* b_own0 = user ? a.b_iu0 : a.b_ui0;
            const float* b_oth0 = user ? a.b_ui0 : a.b_iu0;
            const float* b_own1 = user ? a.b_iu1 : a.b_ui1;
            const float* lin = user ? a.lin_u : a.lin_i;
            const float* bl = user ? a.bl_u : a.bl_i;
            float* o = user ? a.bz_u : a.bz_i;
            float s = bl[n];
            for (int j = 0; j < HID; ++j)
                s += b_own0[j] * S[j * 128 + n] + b_oth0[j] * G[j * 128 + n] +
                     b_own1[j] * lin[(HID + j) * 128 + n];
            o[n] = s;
        }
    } else {
        int cb = b - (SW_B + 386);   // [0, CVT_B)
        int which = (cb >= CVT_PER);
        if (which) cb -= CVT_PER;
        const float4* in = (const float4*)(which ? a.xi : a.xu);
        uint2* outp = (uint2*)(which ? a.xbi : a.xbu);
        const int n4 = NU * DIN / 4;
#pragma unroll
        for (int k = 0; k < 8; ++k) {
            int i = cb * 2048 + k * 256 + t;
            if (i < n4) {
                float4 v = in[i];
                uint2 o;
                o.x = (unsigned int)f2bf(v.x) | ((unsigned int)f2bf(v.y) << 16);
                o.y = (unsigned int)f2bf(v.z) | ((unsigned int)f2bf(v.w) << 16);
                outp[i] = o;
            }
        }
    }
}

// ================= scan3: exclusive scan of totals (reads raw chunk partials) ==========
__global__ __launch_bounds__(256) void scan3(int* __restrict__ d, const int* __restrict__ part,
                                             int n, int nb) {
    __shared__ int wsum[4];
    __shared__ int blockoff_sh;
    int b = blockIdx.x, t = threadIdx.x;
    int lane = t & 63, wv = t >> 6;
    if (t < 64) {
        int v = (t < nb) ? part[t] : 0;
        int incl = v;
#pragma unroll
        for (int off = 1; off < 64; off <<= 1) {
            int tv = __shfl_up(incl, off, 64);
            if (t >= off) incl += tv;
        }
        if (t == b) blockoff_sh = incl - v;
    }
    int i0 = b * 2048 + t * 8;
    int v[8];
    int tsum = 0;
#pragma unroll
    for (int k = 0; k < 8; ++k) {
        v[k] = (i0 + k < n) ? d[i0 + k] : 0;
        tsum += v[k];
    }
    int incl = tsum;
#pragma unroll
    for (int off = 1; off < 64; off <<= 1) {
        int tv = __shfl_up(incl, off, 64);
        if (lane >= off) incl += tv;
    }
    if (lane == 63) wsum[wv] = incl;
    __syncthreads();
    int woff = 0;
    for (int w = 0; w < wv; ++w) woff += wsum[w];
    int run = blockoff_sh + woff + (incl - tsum);
#pragma unroll
    for (int k = 0; k < 8; ++k) {
        if (i0 + k < n) d[i0 + k] = run;
        run += v[k];
    }
}

// ================= fill: quarter-range, uchar slice-offsets -> packed-ushort LDS =======
__global__ __launch_bounds__(256) void fill_lds(const int* __restrict__ eui,
                                                const int* __restrict__ eiu,
                                                const uchar_t* __restrict__ cnt_s,
                                                const int* __restrict__ rowstart,
                                                ushort_t* __restrict__ csr) {
    __shared__ unsigned int off[QN / 2];
    int b = blockIdx.x, t = threadIdx.x;
    int g = b >> 9, s = (b >> 2) & 127, q = b & 3;
    int hbase = q * QN;
    const unsigned int* st =
        (const unsigned int*)(cnt_s + ((size_t)(g * NSLICE + s)) * 50000 + hbase);
    for (int i = t; i < QN / 4; i += 256) {
        unsigned int v = st[i];
        off[2 * i]     = (v & 0xffu) | ((v >> 8) & 0xffu) << 16;
        off[2 * i + 1] = ((v >> 16) & 0xffu) | ((v >> 24) & 0xffu) << 16;
    }
    __syncthreads();
    const int* src = g ? eiu : eui;
    const int* dst = src + NE;
    const int* rs = rowstart + g * 50000;
    int e0 = s * SLICE_SZ;
    for (int i = e0 + t; i < e0 + SLICE_SZ; i += 256) {
        int dd = dst[i];
        int d = dd - hbase;
        if ((unsigned)d < (unsigned)QN) {
            unsigned old = atomicAdd(&off[d >> 1], 1u << ((d & 1) * 16));
            int rel = (int)((old >> ((d & 1) * 16)) & 0xffffu);
            csr[(size_t)rs[dd] + rel] = (ushort_t)src[i];
        }
    }
}

// ================= DIN=128 gather mean aggregation v3: feature-half phases =============
struct AggJob { const int* sp; const ushort_t* csr; const ushort_t* x; ushort_t* out; int n; };
struct AggJobs2 { AggJob j[2]; };

__global__ __launch_bounds__(256) void agg_din(AggJobs2 js) {
    AggJob jb = js.j[blockIdx.y];
    const int half = blockIdx.z;
    int wave = (int)((blockIdx.x * 256u + threadIdx.x) >> 6);
    int lane = threadIdx.x & 63;
    const int l = lane & 15;    // edge slot / feature slot within half
    const int h = lane >> 4;    // row within quad
    int w4 = wave * 4;
    if (w4 >= jb.n) return;
    int w = w4 + h;
    int s0 = jb.sp[w];
    int s1 = jb.sp[w + 1];
    int cnt = s1 - s0;
    float sc = (cnt > 0) ? 1.0f / (float)cnt : 0.0f;
    int cmax = cnt;
    {
        int c1 = __shfl_xor(cmax, 16, 64); cmax = (cmax > c1) ? cmax : c1;
        int c2 = __shfl_xor(cmax, 32, 64); cmax = (cmax > c2) ? cmax : c2;
    }
    const uint2* xp = (const uint2*)jb.x + half * 16;  // row = 32 uint2; half = 16 uint2
    float f0 = 0.f, f1 = 0.f, f2 = 0.f, f3 = 0.f;
#define ACC4(m, u)                                                     \
    f0 = fmaf(m, bf_lo(u.x), f0); f1 = fmaf(m, bf_hi(u.x), f1);        \
    f2 = fmaf(m, bf_lo(u.y), f2); f3 = fmaf(m, bf_hi(u.y), f3);
    for (int chunk = 0; chunk < cmax; chunk += 16) {
        int mh = cnt - chunk;
        int safe = (mh > 0) ? ((l < mh) ? l : mh - 1) : 0;
        int vidx = (int)jb.csr[s0 + chunk + safe];
        int mm = cmax - chunk;
        if (mm > 16) mm = 16;
        int j = 0;
        for (; j + 3 < mm; j += 4) {
            int i0 = __shfl(vidx, j, 16);
            int i1 = __shfl(vidx, j + 1, 16);
            int i2 = __shfl(vidx, j + 2, 16);
            int i3 = __shfl(vidx, j + 3, 16);
            float m0 = (j < mh) ? 1.f : 0.f;
            float m1 = (j + 1 < mh) ? 1.f : 0.f;
            float m2 = (j + 2 < mh) ? 1.f : 0.f;
            float m3 = (j + 3 < mh) ? 1.f : 0.f;
            uint2 u0 = xp[(size_t)((j < mh) ? i0 : 0) * 32 + l];
            uint2 u1 = xp[(size_t)((j + 1 < mh) ? i1 : 0) * 32 + l];
            uint2 u2 = xp[(size_t)((j + 2 < mh) ? i2 : 0) * 32 + l];
            uint2 u3 = xp[(size_t)((j + 3 < mh) ? i3 : 0) * 32 + l];
            ACC4(m0, u0);
            ACC4(m1, u1);
            ACC4(m2, u2);
            ACC4(m3, u3);
        }
        for (; j < mm; ++j) {
            int i0 = __shfl(vidx, j, 16);
            float m0 = (j < mh) ? 1.f : 0.f;
            uint2 u0 = xp[(size_t)((j < mh) ? i0 : 0) * 32 + l];
            ACC4(m0, u0);
        }
    }
#undef ACC4
    uint2 o;
    o.x = (unsigned int)f2bf(f0 * sc) | ((unsigned int)f2bf(f1 * sc) << 16);
    o.y = (unsigned int)f2bf(f2 * sc) | ((unsigned int)f2bf(f3 * sc) << 16);
    ((uint2*)jb.out)[(size_t)w * 32 + half * 16 + l] = o;
}

// ================= MFMA GEMM: C = sum_p A[p]@W[p] + bias, NP parts, 2 jobs =================
struct GemmJob {
    const ushort_t* A[3];
    const ushort_t* WT[3];
    int K[3];
    const float* bias;
    void* C;
};
struct GemmJobs2 { GemmJob j[2]; };

template <int NP, typename OutT>
__global__ __launch_bounds__(256) void gemmN(GemmJobs2 js, int M, int N) {
    GemmJob jb = js.j[blockIdx.z];
    __shared__ ushort_t sA[128 * 32];
    __shared__ ushort_t sB[128 * 32];
    const int tid = threadIdx.x;
    const int lane = tid & 63;
    const int wv = tid >> 6;
    const int wm = wv & 1, wn = wv >> 1;
    const int bm = blockIdx.y * 128, bn = blockIdx.x * 128;

    f32x4 acc[4][4] = {};

    const int srow = tid >> 2;
    const int scol = (tid & 3) * 8;

#pragma unroll
    for (int part = 0; part < NP; ++part) {
        const ushort_t* A = jb.A[part];
        const ushort_t* WT = jb.WT[part];
        const int K = jb.K[part];
        int ar0 = bm + srow;       if (ar0 > M - 1) ar0 = M - 1;
        int ar1 = bm + 64 + srow;  if (ar1 > M - 1) ar1 = M - 1;
        const size_t aoff0 = (size_t)ar0 * K + scol;
        const size_t aoff1 = (size_t)ar1 * K + scol;
        const size_t boff0 = (size_t)(bn + srow) * K + scol;
        const size_t boff1 = (size_t)(bn + 64 + srow) * K + scol;
        for (int k0 = 0; k0 < K; k0 += 32) {
            __syncthreads();
            load_lds16(A + aoff0 + k0, sA + tid * 8);
            load_lds16(A + aoff1 + k0, sA + 2048 + tid * 8);
            load_lds16(WT + boff0 + k0, sB + tid * 8);
            load_lds16(WT + boff1 + k0, sB + 2048 + tid * 8);
            __syncthreads();
            const ushort_t* pA = sA + ((wm * 64 + (lane & 15)) * 32 + (lane >> 4) * 8);
            const ushort_t* pB = sB + ((wn * 64 + (lane & 15)) * 32 + (lane >> 4) * 8);
            bf16x8 af[4], bfr[4];
#pragma unroll
            for (int mt = 0; mt < 4; ++mt) af[mt] = *(const bf16x8*)(pA + mt * 512);
#pragma unroll
            for (int nt = 0; nt < 4; ++nt) bfr[nt] = *(const bf16x8*)(pB + nt * 512);
#pragma unroll
            for (int mt = 0; mt < 4; ++mt)
#pragma unroll
                for (int nt = 0; nt < 4; ++nt)
                    acc[mt][nt] = __builtin_amdgcn_mfma_f32_16x16x32_bf16(
                        af[mt], bfr[nt], acc[mt][nt], 0, 0, 0);
        }
    }

#pragma unroll
    for (int mt = 0; mt < 4; ++mt) {
#pragma unroll
        for (int r = 0; r < 4; ++r) {
            int row = bm + wm * 64 + mt * 16 + (lane >> 4) * 4 + r;
            if (row >= M) continue;
#pragma unroll
            for (int nt = 0; nt < 4; ++nt) {
                int col = bn + wn * 64 + nt * 16 + (lane & 15);
                float v = acc[mt][nt][r] + jb.bias[col];
                if constexpr (sizeof(OutT) == 2)
                    ((ushort_t*)jb.C)[(size_t)row * N + col] = f2bf(v);
                else
                    ((float*)jb.C)[(size_t)row * N + col] = v;
            }
        }
    }
}

// ================= decode: bf16 z, 4 edges per wave (16-lane quarters, uint4) =================
__global__ void decode_kernel(const int* __restrict__ lbl, const ushort_t* __restrict__ zu,
                              const ushort_t* __restrict__ zi, float* __restrict__ out, int n) {
    int gid = blockIdx.x * blockDim.x + threadIdx.x;
    int wave = gid >> 6;
    int lane = threadIdx.x & 63;
    int q = lane >> 4;
    int l = lane & 15;
    int e = wave * 4 + q;
    if (e >= n) return;
    int u = lbl[e];
    int it = lbl[n + e];
    uint4 a = ((const uint4*)zu)[(size_t)u * 16 + l];
    uint4 b = ((const uint4*)zi)[(size_t)it * 16 + l];
    float s = bf_lo(a.x) * bf_lo(b.x) + bf_hi(a.x) * bf_hi(b.x) +
              bf_lo(a.y) * bf_lo(b.y) + bf_hi(a.y) * bf_hi(b.y) +
              bf_lo(a.z) * bf_lo(b.z) + bf_hi(a.z) * bf_hi(b.z) +
              bf_lo(a.w) * bf_lo(b.w) + bf_hi(a.w) * bf_hi(b.w);
#pragma unroll
    for (int off = 8; off > 0; off >>= 1) s += __shfl_down(s, off, 16);
    if (l == 0) out[e] = s;
}

extern "C" void kernel_launch(void* const* d_in, const int* in_sizes, int n_in,
                              void* d_out, int out_size, void* d_ws, size_t ws_size,
                              hipStream_t stream) {
    const float* x_user = (const float*)d_in[0];
    const float* x_item = (const float*)d_in[1];
    const int* edge_ui = (const int*)d_in[2];   // row0=src(user), row1=dst(item)
    const int* edge_iu = (const int*)d_in[3];   // row0=src(item), row1=dst(user)
    const int* edge_lbl = (const int*)d_in[4];
    const float* w_msg_ui0 = (const float*)d_in[5];
    const float* b_ui0 = (const float*)d_in[6];
    const float* w_root_ui0 = (const float*)d_in[7];
    const float* w_msg_iu0 = (const float*)d_in[8];
    const float* b_iu0 = (const float*)d_in[9];
    const float* w_root_iu0 = (const float*)d_in[10];
    const float* w_msg_ui1 = (const float*)d_in[11];
    const float* b_ui1 = (const float*)d_in[12];
    const float* w_root_ui1 = (const float*)d_in[13];
    const float* w_msg_iu1 = (const float*)d_in[14];
    const float* b_iu1 = (const float*)d_in[15];
    const float* w_root_iu1 = (const float*)d_in[16];
    const float* w_lin_u = (const float*)d_in[17];  // [512,128]
    const float* b_lin_u = (const float*)d_in[18];
    const float* w_lin_i = (const float*)d_in[19];
    const float* b_lin_i = (const float*)d_in[20];
    float* out = (float*)d_out;

    // ---- workspace layout ----
    char* p = (char*)d_ws;
    ushort_t* A_i  = (ushort_t*)p;   p += (size_t)NI * DIN * 2;  // mean_ui(x_user)
    ushort_t* A_u  = (ushort_t*)p;   p += (size_t)NU * DIN * 2;  // mean_iu(x_item)
    ushort_t* B_i  = (ushort_t*)p;   p += (size_t)NI * DIN * 2;  // mean_ui(A_u)
    ushort_t* B_u  = (ushort_t*)p;   p += (size_t)NU * DIN * 2;  // mean_iu(A_i)
    ushort_t* xb_u  = (ushort_t*)p;  p += (size_t)NU * DIN * 2;
    ushort_t* xb_i  = (ushort_t*)p;  p += (size_t)NI * DIN * 2;
    ushort_t* z_user = (ushort_t*)p; p += (size_t)NU * DOUT * 2;
    ushort_t* z_item = (ushort_t*)p; p += (size_t)NI * DOUT * 2;
    int* totals     = (int*)p;       p += (size_t)(100000 + 64) * 4;  // rowstarts + sentinel
    ushort_t* csr   = (ushort_t*)p;  p += (size_t)2 * NE * 2;  // [0,NE): ui; [NE,2NE): iu
    uchar_t* cnt_s  = (uchar_t*)p;   p += (size_t)2 * NSLICE * 50000;  // per-slice uchar counts
    int* scan_part  = (int*)p;       p += 64 * 4;
    float* G_i = (float*)p; p += (size_t)HID * 128 * 4;
    float* S_i = (float*)p; p += (size_t)HID * 128 * 4;
    float* G_u = (float*)p; p += (size_t)HID * 128 * 4;
    float* S_u = (float*)p; p += (size_t)HID * 128 * 4;
    ushort_t* VT1_i = (ushort_t*)p; p += (size_t)128 * 128 * 2;
    ushort_t* VT2_i = (ushort_t*)p; p += (size_t)128 * 128 * 2;
    ushort_t* VT3_i = (ushort_t*)p; p += (size_t)128 * 128 * 2;
    ushort_t* VT1_u = (ushort_t*)p; p += (size_t)128 * 128 * 2;
    ushort_t* VT2_u = (ushort_t*)p; p += (size_t)128 * 128 * 2;
    ushort_t* VT3_u = (ushort_t*)p; p += (size_t)128 * 128 * 2;
    float* bz_i = (float*)p; p += 128 * 4;
    float* bz_u = (float*)p; p += 128 * 4;

    const int NCNT = 100000;
    const int NB = (NCNT + 2047) / 2048;  // 49

    // ---- 1: hist (uchar, quarter-range) ∥ stage-A products ∥ scan_part zero ----
    P1Args p1;
    p1.eui = edge_ui; p1.eiu = edge_iu; p1.cnt_s = cnt_s;
    p1.wm_ui1 = w_msg_ui1; p1.wr_ui1 = w_root_ui1;
    p1.wm_iu1 = w_msg_iu1; p1.wr_iu1 = w_root_iu1;
    p1.lin_i = w_lin_i; p1.lin_u = w_lin_u;
    p1.G_i = G_i; p1.S_i = S_i; p1.G_u = G_u; p1.S_u = S_u;
    p1.scan_part = scan_part;
    phase1<<<HIST_B + SA_B + 1, 256, 0, stream>>>(p1);

    // ---- 2: coalesced uchar sscan (+scan1 fold) ∥ prep2 V products + bz ∥ cvt ----
    K2Args k2;
    k2.cnt_s = cnt_s; k2.totals = totals; k2.scan_part = scan_part;
    k2.wm_ui0 = w_msg_ui0; k2.wr_ui0 = w_root_ui0;
    k2.wm_iu0 = w_msg_iu0; k2.wr_iu0 = w_root_iu0;
    k2.G_i = G_i; k2.S_i = S_i; k2.G_u = G_u; k2.S_u = S_u;
    k2.b_ui0 = b_ui0; k2.b_iu0 = b_iu0; k2.b_ui1 = b_ui1; k2.b_iu1 = b_iu1;
    k2.lin_i = w_lin_i; k2.lin_u = w_lin_u; k2.bl_i = b_lin_i; k2.bl_u = b_lin_u;
    k2.VT1_i = VT1_i; k2.VT2_i = VT2_i; k2.VT3_i = VT3_i;
    k2.VT1_u = VT1_u; k2.VT2_u = VT2_u; k2.VT3_u = VT3_u;
    k2.bz_i = bz_i; k2.bz_u = bz_u;
    k2.xu = x_user; k2.xbu = xb_u; k2.xi = x_item; k2.xbi = xb_i;
    k2_scan_prep_cvt<<<SW_B + 386 + CVT_B, 256, 0, stream>>>(k2);

    // ---- 3: global scan (scan3 reads raw chunk partials, scans internally) ----
    scan3<<<NB, 256, 0, stream>>>(totals, scan_part, NCNT, NB);

    // ---- 4: fill csr (quarter-range, 1024 blocks) ----
    fill_lds<<<HIST_B, 256, 0, stream>>>(edge_ui, edge_iu, cnt_s, totals, csr);

    // ---- 5: level-A aggregation (feature-half phases via blockIdx.z) ----
    {
        AggJobs2 aj = {{{totals, csr, xb_u, A_i, NI},
                        {totals + 50000, csr, xb_i, A_u, NU}}};
        agg_din<<<dim3(3125, 2, 2), 256, 0, stream>>>(aj);
    }
    // ---- 6: level-B aggregation: B_i = mean_ui(A_u), B_u = mean_iu(A_i) ----
    {
        AggJobs2 aj = {{{totals, csr, A_u, B_i, NI},
                        {totals + 50000, csr, A_i, B_u, NU}}};
        agg_din<<<dim3(3125, 2, 2), 256, 0, stream>>>(aj);
    }

    // ---- 7: single fused-weight GEMM: z = A@V1 + xb@V2 + B@V3 + bz ----
    {
        GemmJobs2 gj = {{{{A_i, xb_i, B_i}, {VT1_i, VT2_i, VT3_i}, {DIN, DIN, DIN}, bz_i, z_item},
                         {{A_u, xb_u, B_u}, {VT1_u, VT2_u, VT3_u}, {DIN, DIN, DIN}, bz_u, z_user}}};
        gemmN<3, ushort_t><<<dim3(DOUT / 128, (NU + 127) / 128, 2), 256, 0, stream>>>(gj, NU, DOUT);
    }

    // ---- 8: decode (4 edges per wave) ----
    decode_kernel<<<(((NLBL + 3) / 4) * 64 + 255) / 256, 256, 0, stream>>>(
        edge_lbl, z_user, z_item, out, NLBL);
}